// Round 1
// baseline (216.722 us; speedup 1.0000x reference)
//
#include <hip/hip_runtime.h>

#define WIN 7
#define IMH 384
#define IMW 384
#define OH 378
#define OW 378
#define NB 64
#define TILE 32
#define IN_T 38   // TILE + WIN - 1
#define LDSTR 40  // padded LDS row stride (floats)

__global__ __launch_bounds__(256) void ssim_kernel(
    const float* __restrict__ X, const float* __restrict__ Y,
    const float* __restrict__ data_range, float* __restrict__ acc)
{
    __shared__ float xs[IN_T][LDSTR];
    __shared__ float ys[IN_T][LDSTR];
    __shared__ float vs[5][TILE][LDSTR];
    __shared__ float red[4];

    const int tid  = threadIdx.x;
    const int b    = blockIdx.z;
    const int row0 = blockIdx.y * TILE;
    const int col0 = blockIdx.x * TILE;
    const float* __restrict__ Xb = X + b * (IMH * IMW);
    const float* __restrict__ Yb = Y + b * (IMH * IMW);

    // ---- Stage A: global -> LDS halo tile (38x38), coalesced-ish rows ----
    for (int i = tid; i < IN_T * IN_T; i += 256) {
        int r = i / IN_T;
        int c = i - r * IN_T;
        int gr = row0 + r, gc = col0 + c;
        float xv = 0.f, yv = 0.f;
        if (gr < IMH && gc < IMW) {
            xv = Xb[gr * IMW + gc];
            yv = Yb[gr * IMW + gc];
        }
        xs[r][c] = xv;
        ys[r][c] = yv;
    }
    __syncthreads();

    // ---- Stage B: vertical 7-sums of 5 products for 32 out-rows x 38 cols ----
    for (int u = tid; u < TILE * IN_T; u += 256) {
        int ly = u / IN_T;
        int c  = u - ly * IN_T;
        float sx = 0.f, sy = 0.f, sxx = 0.f, sxy = 0.f, syy = 0.f;
        #pragma unroll
        for (int k = 0; k < WIN; ++k) {
            float x = xs[ly + k][c];
            float y = ys[ly + k][c];
            sx += x;
            sy += y;
            sxx = fmaf(x, x, sxx);
            sxy = fmaf(x, y, sxy);
            syy = fmaf(y, y, syy);
        }
        vs[0][ly][c] = sx;
        vs[1][ly][c] = sy;
        vs[2][ly][c] = sxx;
        vs[3][ly][c] = sxy;
        vs[4][ly][c] = syy;
    }
    __syncthreads();

    // ---- Stage C: horizontal 7-sums via sliding window; 4 px/thread ----
    const int ly  = tid >> 3;        // 0..31
    const int cx0 = (tid & 7) * 4;   // 0,4,...,28 (16B aligned)
    float s[5][4];
    #pragma unroll
    for (int p = 0; p < 5; ++p) {
        const float* vp = &vs[p][ly][cx0];
        float4 a  = *(const float4*)(vp);
        float4 bq = *(const float4*)(vp + 4);
        float2 cq = *(const float2*)(vp + 8);
        float v0 = a.x, v1 = a.y, v2 = a.z, v3 = a.w;
        float v4 = bq.x, v5 = bq.y, v6 = bq.z, v7 = bq.w;
        float v8 = cq.x, v9 = cq.y;
        float w0 = ((v0 + v1) + (v2 + v3)) + ((v4 + v5) + v6);
        float w1 = w0 - v0 + v7;
        float w2 = w1 - v1 + v8;
        float w3 = w2 - v2 + v9;
        s[p][0] = w0; s[p][1] = w1; s[p][2] = w2; s[p][3] = w3;
    }

    const float L     = data_range[b];
    const float C1    = (0.01f * L) * (0.01f * L);
    const float C2    = (0.03f * L) * (0.03f * L);
    const float inv49 = 1.0f / 49.0f;
    const float covn  = 49.0f / 48.0f;   // unbiased covariance correction

    float lsum = 0.f;
    const int orow = row0 + ly;
    #pragma unroll
    for (int j = 0; j < 4; ++j) {
        int ocol = col0 + cx0 + j;
        if (orow < OH && ocol < OW) {
            float ux  = s[0][j] * inv49;
            float uy  = s[1][j] * inv49;
            float vx  = (s[2][j] * inv49 - ux * ux) * covn;
            float vy  = (s[4][j] * inv49 - uy * uy) * covn;
            float vxy = (s[3][j] * inv49 - ux * uy) * covn;
            float N1 = 2.f * ux * uy + C1;
            float N2 = 2.f * vxy + C2;
            float D1 = ux * ux + uy * uy + C1;
            float D2 = vx + vy + C2;
            lsum += (N1 * N2) / (D1 * D2);
        }
    }

    // ---- Block reduction: wave64 shuffle -> LDS -> one atomic/block ----
    #pragma unroll
    for (int off = 32; off > 0; off >>= 1)
        lsum += __shfl_down(lsum, off, 64);
    if ((tid & 63) == 0) red[tid >> 6] = lsum;
    __syncthreads();
    if (tid == 0) {
        float bs = (red[0] + red[1]) + (red[2] + red[3]);
        atomicAdd(acc, bs);
    }
}

__global__ void finalize_kernel(const float* __restrict__ acc,
                                float* __restrict__ out)
{
    out[0] = 1.0f - acc[0] * (1.0f / (float)(NB * OH * OW));
}

extern "C" void kernel_launch(void* const* d_in, const int* in_sizes, int n_in,
                              void* d_out, int out_size, void* d_ws, size_t ws_size,
                              hipStream_t stream) {
    const float* X  = (const float*)d_in[0];
    const float* Y  = (const float*)d_in[1];
    const float* dr = (const float*)d_in[2];
    float* out = (float*)d_out;
    float* acc = (float*)d_ws;

    hipMemsetAsync(acc, 0, sizeof(float), stream);

    dim3 grid((OW + TILE - 1) / TILE, (OH + TILE - 1) / TILE, NB);  // 12x12x64
    dim3 block(256);
    ssim_kernel<<<grid, block, 0, stream>>>(X, Y, dr, acc);
    finalize_kernel<<<1, 1, 0, stream>>>(acc, out);
}

// Round 2
// 145.115 us; speedup vs baseline: 1.4934x; 1.4934x over previous
//
#include <hip/hip_runtime.h>

#define IMH 384
#define IMW 384
#define OH 378
#define OW 378
#define NB 64
#define SROWS 36          // output rows per strip
#define NSTRIP 11         // 11*36 = 396 >= 378
#define INROWS 42         // SROWS + 6, multiple of 7 for clean unroll

// One thread per column; walks down a 42-input-row strip.
// Horizontal 7-window sums computed per row from overlapping global loads
// (L1-served); vertical 7-window via register circular buffer (add/sub).
__global__ __launch_bounds__(384, 4) void ssim_kernel(
    const float* __restrict__ X, const float* __restrict__ Y,
    const float* __restrict__ data_range, float* __restrict__ acc)
{
    const int tid   = threadIdx.x;
    const int strip = blockIdx.x;
    const int b     = blockIdx.y;
    const int y0    = strip * SROWS;

    const float* __restrict__ Xb = X + b * (IMH * IMW);
    const float* __restrict__ Yb = Y + b * (IMH * IMW);

    const int  c      = tid;
    const int  cc     = min(c, OW - 1);   // clamp so loads never go OOB
    const bool cvalid = (c < OW);

    const float L     = data_range[b];
    const float C1    = (0.01f * L) * (0.01f * L);
    const float C2    = (0.03f * L) * (0.03f * L);
    const float inv49 = 1.0f / 49.0f;
    const float covn  = 49.0f / 48.0f;    // unbiased covariance correction

    // Circular history of horizontal sums (7 rows x 5 products) + running
    // vertical sums. All register-resident (indices static after unroll).
    float H[7][5];
    float V[5];
    #pragma unroll
    for (int k = 0; k < 7; ++k)
        #pragma unroll
        for (int p = 0; p < 5; ++p) H[k][p] = 0.f;
    #pragma unroll
    for (int p = 0; p < 5; ++p) V[p] = 0.f;

    float lsum = 0.f;

    for (int rb = 0; rb < INROWS; rb += 7) {
        #pragma unroll
        for (int k = 0; k < 7; ++k) {
            const int r  = rb + k;
            const int ri = min(y0 + r, IMH - 1);   // uniform (SGPR) row clamp
            const float* xr = Xb + ri * IMW + cc;
            const float* yr = Yb + ri * IMW + cc;

            // 7-wide window via two overlapping 16B loads per image.
            float xw[7], yw[7];
            __builtin_memcpy(&xw[0], xr, 16);       // cols c..c+3
            __builtin_memcpy(&xw[3], xr + 3, 16);   // cols c+3..c+6
            __builtin_memcpy(&yw[0], yr, 16);
            __builtin_memcpy(&yw[3], yr + 3, 16);

            float sx = 0.f, sy = 0.f, sxx = 0.f, sxy = 0.f, syy = 0.f;
            #pragma unroll
            for (int j = 0; j < 7; ++j) {
                sx += xw[j];
                sy += yw[j];
                sxx = fmaf(xw[j], xw[j], sxx);
                sxy = fmaf(xw[j], yw[j], sxy);
                syy = fmaf(yw[j], yw[j], syy);
            }

            H[k][0] = sx;  H[k][1] = sy;  H[k][2] = sxx;
            H[k][3] = sxy; H[k][4] = syy;
            V[0] += sx; V[1] += sy; V[2] += sxx; V[3] += sxy; V[4] += syy;
            // V now covers input rows [y0+r-6 .. y0+r] (older slots are 0)

            const int o = y0 + r - 6;               // output row
            if (r >= 6 && o < OH) {                 // uniform branch
                float ux   = V[0] * inv49;
                float uy   = V[1] * inv49;
                float uxux = ux * ux, uyuy = uy * uy, uxuy = ux * uy;
                float vx   = (V[2] * inv49 - uxux) * covn;
                float vy   = (V[4] * inv49 - uyuy) * covn;
                float vxy  = (V[3] * inv49 - uxuy) * covn;
                float N1 = fmaf(2.f, uxuy, C1);
                float N2 = fmaf(2.f, vxy, C2);
                float D1 = uxux + uyuy + C1;
                float D2 = vx + vy + C2;
                float sval = (N1 * N2) * __builtin_amdgcn_rcpf(D1 * D2);
                lsum += cvalid ? sval : 0.f;
            }

            // Retire row r-6 (slot (r+1)%7 == (k+1)%7); it is overwritten
            // next iteration. Slots for pre-strip rows hold 0 -> harmless.
            const int kn = (k + 1) % 7;
            #pragma unroll
            for (int p = 0; p < 5; ++p) V[p] -= H[kn][p];
        }
    }

    // ---- Block reduction: wave64 shuffle -> LDS -> one atomic/block ----
    __shared__ float red[6];
    #pragma unroll
    for (int off = 32; off > 0; off >>= 1)
        lsum += __shfl_down(lsum, off, 64);
    if ((tid & 63) == 0) red[tid >> 6] = lsum;
    __syncthreads();
    if (tid == 0) {
        float bs = ((red[0] + red[1]) + (red[2] + red[3])) + (red[4] + red[5]);
        atomicAdd(acc, bs);
    }
}

__global__ void finalize_kernel(const float* __restrict__ acc,
                                float* __restrict__ out)
{
    out[0] = 1.0f - acc[0] * (1.0f / (float)(NB * OH * OW));
}

extern "C" void kernel_launch(void* const* d_in, const int* in_sizes, int n_in,
                              void* d_out, int out_size, void* d_ws, size_t ws_size,
                              hipStream_t stream) {
    const float* X  = (const float*)d_in[0];
    const float* Y  = (const float*)d_in[1];
    const float* dr = (const float*)d_in[2];
    float* out = (float*)d_out;
    float* acc = (float*)d_ws;

    hipMemsetAsync(acc, 0, sizeof(float), stream);

    dim3 grid(NSTRIP, NB);   // 11 x 64 = 704 blocks
    dim3 block(384);         // one thread per column (6 waves)
    ssim_kernel<<<grid, block, 0, stream>>>(X, Y, dr, acc);
    finalize_kernel<<<1, 1, 0, stream>>>(acc, out);
}